// Round 1
// baseline (2831.382 us; speedup 1.0000x reference)
//
#include <hip/hip_runtime.h>
#include <cstdint>

#define DIM   128
#define BPAD  132   // LDS row pitch for B (padding breaks staging-write conflicts)

// ---------------------------------------------------------------------------
// Kernel 1: T[n][j] = sum_k A[n][k] * W[j][k]   (A @ W^T), fp32 vector ALU.
// W (64 KB) staged in LDS transposed as Bs[k][j]. Thread tile: 4 rows x 16
// cols, with column ownership j in {cg*4 + 32*m} so the ds_read_b128 of B is
// bank-conflict-free (8 distinct 16B chunks -> disjoint 4-bank groups; the 8
// row-groups broadcast).
// ---------------------------------------------------------------------------
__global__ __launch_bounds__(256) void gnn_transform(
    const float* __restrict__ A,   // [n, 128] node_emb
    const float* __restrict__ W,   // [128, 128] row-major
    float* __restrict__ T,         // [n, 128] output (workspace)
    int n)
{
    __shared__ float Bs[DIM * BPAD];   // Bs[k*BPAD + j] = W[j][k]

    // Stage W transposed: thread t handles j = t/2, k-half = (t&1)*64.
    {
        const int j  = threadIdx.x >> 1;
        const int k0 = (threadIdx.x & 1) << 6;
        const float* wr = W + j * DIM + k0;
#pragma unroll
        for (int k = 0; k < 64; k += 4) {
            float4 v = *(const float4*)(wr + k);
            Bs[(k0 + k + 0) * BPAD + j] = v.x;
            Bs[(k0 + k + 1) * BPAD + j] = v.y;
            Bs[(k0 + k + 2) * BPAD + j] = v.z;
            Bs[(k0 + k + 3) * BPAD + j] = v.w;
        }
    }
    __syncthreads();

    const int cg = threadIdx.x & 7;    // col group: owns cols cg*4 + 32*m, m=0..3
    const int rg = threadIdx.x >> 3;   // row group 0..31: rows rg*4 .. rg*4+3
    const int ntiles = (n + 127) >> 7; // 128 rows per block-tile

    for (int tile = blockIdx.x; tile < ntiles; tile += gridDim.x) {
        const int r0 = (tile << 7) + (rg << 2);

        float acc[4][16];
#pragma unroll
        for (int i = 0; i < 4; ++i)
#pragma unroll
            for (int m = 0; m < 16; ++m) acc[i][m] = 0.f;

        // Clamp row indices so vector loads stay in-bounds on the tail tile.
        int rr[4];
#pragma unroll
        for (int i = 0; i < 4; ++i) {
            int r = r0 + i;
            rr[i] = (r < n) ? r : (n - 1);
        }

        for (int k0 = 0; k0 < DIM; k0 += 4) {
            float4 a[4];
#pragma unroll
            for (int i = 0; i < 4; ++i)
                a[i] = *(const float4*)(A + (size_t)rr[i] * DIM + k0);

#pragma unroll
            for (int kk = 0; kk < 4; ++kk) {
#pragma unroll
                for (int m = 0; m < 4; ++m) {
                    const float4 b = *(const float4*)(
                        &Bs[(k0 + kk) * BPAD + (cg << 2) + (m << 5)]);
#pragma unroll
                    for (int i = 0; i < 4; ++i) {
                        const float ak = (kk == 0) ? a[i].x :
                                         (kk == 1) ? a[i].y :
                                         (kk == 2) ? a[i].z : a[i].w;
                        acc[i][m * 4 + 0] += ak * b.x;
                        acc[i][m * 4 + 1] += ak * b.y;
                        acc[i][m * 4 + 2] += ak * b.z;
                        acc[i][m * 4 + 3] += ak * b.w;
                    }
                }
            }
        }

#pragma unroll
        for (int i = 0; i < 4; ++i) {
            const int r = r0 + i;
            if (r < n) {
                float* o = T + (size_t)r * DIM;
#pragma unroll
                for (int m = 0; m < 4; ++m) {
                    float4 v = make_float4(acc[i][m * 4 + 0], acc[i][m * 4 + 1],
                                           acc[i][m * 4 + 2], acc[i][m * 4 + 3]);
                    *(float4*)(o + (cg << 2) + (m << 5)) = v;
                }
            }
        }
    }
}

// ---------------------------------------------------------------------------
// Kernel 2: for each edge e: out[dst[e]][:] += T[src[e]][:] * w[e]
// 32 lanes per edge, float4 per lane, native f32 atomics into d_out.
// ---------------------------------------------------------------------------
__global__ __launch_bounds__(256) void gnn_scatter(
    const float* __restrict__ T,
    const float* __restrict__ ew,
    const int*   __restrict__ src,
    const int*   __restrict__ dst,
    float* __restrict__ out,
    int n_edges)
{
    const int tid = blockIdx.x * 256 + threadIdx.x;
    const int e = tid >> 5;
    if (e >= n_edges) return;
    const int l = tid & 31;

    const int   s = src[e];
    const int   d = dst[e];
    const float w = ew[e];

    const float4 v = ((const float4*)(T + (size_t)s * DIM))[l];
    float* o = out + (size_t)d * DIM + (l << 2);

#if defined(__gfx90a__) || defined(__gfx940__) || defined(__gfx941__) || \
    defined(__gfx942__) || defined(__gfx950__)
    unsafeAtomicAdd(o + 0, v.x * w);
    unsafeAtomicAdd(o + 1, v.y * w);
    unsafeAtomicAdd(o + 2, v.z * w);
    unsafeAtomicAdd(o + 3, v.w * w);
#else
    atomicAdd(o + 0, v.x * w);
    atomicAdd(o + 1, v.y * w);
    atomicAdd(o + 2, v.z * w);
    atomicAdd(o + 3, v.w * w);
#endif
}

// ---------------------------------------------------------------------------
// inputs: 0=node_emb [100000*128] f32, 1=edge_weight [1.6M] f32,
//         2=src [1.6M] i32, 3=dst [1.6M] i32, 4=W [128*128] f32
// out: [100000*128] f32.  ws: T = node_emb @ W^T (51.2 MB).
// ---------------------------------------------------------------------------
extern "C" void kernel_launch(void* const* d_in, const int* in_sizes, int n_in,
                              void* d_out, int out_size, void* d_ws, size_t ws_size,
                              hipStream_t stream)
{
    const float* node_emb = (const float*)d_in[0];
    const float* ew       = (const float*)d_in[1];
    const int*   src      = (const int*)d_in[2];
    const int*   dst      = (const int*)d_in[3];
    const float* W        = (const float*)d_in[4];
    float* out = (float*)d_out;
    float* T   = (float*)d_ws;

    const int n_nodes = in_sizes[0] / DIM;
    const int n_edges = in_sizes[1];

    // 1) zero the accumulator output (harness poisons it with 0xAA)
    hipMemsetAsync(d_out, 0, (size_t)out_size * sizeof(float), stream);

    // 2) T = node_emb @ W^T
    const int ntiles = (n_nodes + 127) >> 7;
    gnn_transform<<<ntiles, 256, 0, stream>>>(node_emb, W, T, n_nodes);

    // 3) out[dst] += T[src] * w   (atomics)
    const int nthreads = n_edges * 32;
    gnn_scatter<<<(nthreads + 255) / 256, 256, 0, stream>>>(
        T, ew, src, dst, out, n_edges);
}

// Round 2
// 455.333 us; speedup vs baseline: 6.2183x; 6.2183x over previous
//
#include <hip/hip_runtime.h>
#include <cstdint>

#define DIM   128
#define BPAD  132

// ---------------------------------------------------------------------------
// Kernel 1: T = node_emb @ W^T  (fp32 vector ALU; W staged transposed in LDS)
// ---------------------------------------------------------------------------
__global__ __launch_bounds__(256) void gnn_transform(
    const float* __restrict__ A, const float* __restrict__ W,
    float* __restrict__ T, int n)
{
    __shared__ float Bs[DIM * BPAD];
    {
        const int j  = threadIdx.x >> 1;
        const int k0 = (threadIdx.x & 1) << 6;
        const float* wr = W + j * DIM + k0;
#pragma unroll
        for (int k = 0; k < 64; k += 4) {
            float4 v = *(const float4*)(wr + k);
            Bs[(k0 + k + 0) * BPAD + j] = v.x;
            Bs[(k0 + k + 1) * BPAD + j] = v.y;
            Bs[(k0 + k + 2) * BPAD + j] = v.z;
            Bs[(k0 + k + 3) * BPAD + j] = v.w;
        }
    }
    __syncthreads();

    const int cg = threadIdx.x & 7;
    const int rg = threadIdx.x >> 3;
    const int ntiles = (n + 127) >> 7;

    for (int tile = blockIdx.x; tile < ntiles; tile += gridDim.x) {
        const int r0 = (tile << 7) + (rg << 2);
        float acc[4][16];
#pragma unroll
        for (int i = 0; i < 4; ++i)
#pragma unroll
            for (int m = 0; m < 16; ++m) acc[i][m] = 0.f;

        int rr[4];
#pragma unroll
        for (int i = 0; i < 4; ++i) {
            int r = r0 + i;
            rr[i] = (r < n) ? r : (n - 1);
        }

        for (int k0 = 0; k0 < DIM; k0 += 4) {
            float4 a[4];
#pragma unroll
            for (int i = 0; i < 4; ++i)
                a[i] = *(const float4*)(A + (size_t)rr[i] * DIM + k0);
#pragma unroll
            for (int kk = 0; kk < 4; ++kk) {
#pragma unroll
                for (int m = 0; m < 4; ++m) {
                    const float4 b = *(const float4*)(
                        &Bs[(k0 + kk) * BPAD + (cg << 2) + (m << 5)]);
#pragma unroll
                    for (int i = 0; i < 4; ++i) {
                        const float ak = (kk == 0) ? a[i].x :
                                         (kk == 1) ? a[i].y :
                                         (kk == 2) ? a[i].z : a[i].w;
                        acc[i][m * 4 + 0] += ak * b.x;
                        acc[i][m * 4 + 1] += ak * b.y;
                        acc[i][m * 4 + 2] += ak * b.z;
                        acc[i][m * 4 + 3] += ak * b.w;
                    }
                }
            }
        }
#pragma unroll
        for (int i = 0; i < 4; ++i) {
            const int r = r0 + i;
            if (r < n) {
                float* o = T + (size_t)r * DIM;
#pragma unroll
                for (int m = 0; m < 4; ++m) {
                    float4 v = make_float4(acc[i][m*4+0], acc[i][m*4+1],
                                           acc[i][m*4+2], acc[i][m*4+3]);
                    *(float4*)(o + (cg << 2) + (m << 5)) = v;
                }
            }
        }
    }
}

// ---------------------------------------------------------------------------
// Counting sort by dst: histogram -> scan -> scatter (CSR build)
// ---------------------------------------------------------------------------
__global__ __launch_bounds__(256) void edge_hist(
    const int* __restrict__ dst, int* __restrict__ cnt, int nE)
{
    int i = blockIdx.x * 256 + threadIdx.x;
    if (i < nE) atomicAdd(&cnt[dst[i]], 1);
}

// Phase 1: per-1024-bin block sums
__global__ __launch_bounds__(256) void scan_phase1(
    const int* __restrict__ cnt, int* __restrict__ bsum, int n)
{
    const int base = blockIdx.x << 10;
    int s = 0;
    for (int i = threadIdx.x; i < 1024; i += 256) {
        int idx = base + i;
        if (idx < n) s += cnt[idx];
    }
    __shared__ int red[256];
    red[threadIdx.x] = s; __syncthreads();
    for (int o = 128; o; o >>= 1) {
        if (threadIdx.x < o) red[threadIdx.x] += red[threadIdx.x + o];
        __syncthreads();
    }
    if (threadIdx.x == 0) bsum[blockIdx.x] = red[0];
}

// Phase 2: serial exclusive scan of block sums (nb ~ 98)
__global__ void scan_phase2(int* __restrict__ bsum, int nb)
{
    if (threadIdx.x == 0 && blockIdx.x == 0) {
        int run = 0;
        for (int i = 0; i < nb; ++i) { int t = bsum[i]; bsum[i] = run; run += t; }
    }
}

// Phase 3: in-place exclusive scan of cnt -> off; also cur = off; off[n] = E
__global__ __launch_bounds__(256) void scan_phase3(
    int* __restrict__ off, const int* __restrict__ bsumEx,
    int* __restrict__ cur, int n, int E)
{
    const int base = blockIdx.x << 10;
    const int i0 = base + threadIdx.x * 4;
    int c[4]; int s = 0;
#pragma unroll
    for (int k = 0; k < 4; ++k) {
        int idx = i0 + k;
        c[k] = (idx < n) ? off[idx] : 0;
        s += c[k];
    }
    __shared__ int sc[256];
    sc[threadIdx.x] = s; __syncthreads();
    for (int d = 1; d < 256; d <<= 1) {
        int v = (threadIdx.x >= d) ? sc[threadIdx.x - d] : 0;
        __syncthreads();
        sc[threadIdx.x] += v;
        __syncthreads();
    }
    int run = bsumEx[blockIdx.x] + (sc[threadIdx.x] - s);
#pragma unroll
    for (int k = 0; k < 4; ++k) {
        int idx = i0 + k;
        if (idx < n) { off[idx] = run; cur[idx] = run; run += c[k]; }
    }
    if (blockIdx.x == 0 && threadIdx.x == 0) off[n] = E;
}

__global__ __launch_bounds__(256) void edge_build(
    const int* __restrict__ src, const int* __restrict__ dst,
    const float* __restrict__ w, int* __restrict__ cur,
    int* __restrict__ ssrc, float* __restrict__ sw, int nE)
{
    int i = blockIdx.x * 256 + threadIdx.x;
    if (i < nE) {
        int d = dst[i];
        int p = atomicAdd(&cur[d], 1);
        ssrc[p] = src[i];
        sw[p]   = w[i];
    }
}

// ---------------------------------------------------------------------------
// Aggregate: 32 lanes/node, float4/lane; serial over the node's edge list.
// Writes out exactly once per node -> no atomics, no output memset needed.
// ---------------------------------------------------------------------------
__global__ __launch_bounds__(256) void gnn_aggregate(
    const float* __restrict__ T, const int* __restrict__ off,
    const int* __restrict__ ssrc, const float* __restrict__ sw,
    float* __restrict__ out, int n)
{
    const int tid = blockIdx.x * 256 + threadIdx.x;
    const int v = tid >> 5;
    if (v >= n) return;
    const int lane = tid & 31;

    const int b = off[v], e = off[v + 1];
    float4 acc = make_float4(0.f, 0.f, 0.f, 0.f);

    int i = b;
    for (; i + 1 < e; i += 2) {
        const int   s0 = ssrc[i],   s1 = ssrc[i + 1];
        const float w0 = sw[i],     w1 = sw[i + 1];
        const float4 t0 = ((const float4*)(T + (size_t)s0 * DIM))[lane];
        const float4 t1 = ((const float4*)(T + (size_t)s1 * DIM))[lane];
        acc.x += w0 * t0.x; acc.y += w0 * t0.y;
        acc.z += w0 * t0.z; acc.w += w0 * t0.w;
        acc.x += w1 * t1.x; acc.y += w1 * t1.y;
        acc.z += w1 * t1.z; acc.w += w1 * t1.w;
    }
    if (i < e) {
        const int   s0 = ssrc[i];
        const float w0 = sw[i];
        const float4 t0 = ((const float4*)(T + (size_t)s0 * DIM))[lane];
        acc.x += w0 * t0.x; acc.y += w0 * t0.y;
        acc.z += w0 * t0.z; acc.w += w0 * t0.w;
    }
    ((float4*)(out + (size_t)v * DIM))[lane] = acc;
}

// ---------------------------------------------------------------------------
extern "C" void kernel_launch(void* const* d_in, const int* in_sizes, int n_in,
                              void* d_out, int out_size, void* d_ws, size_t ws_size,
                              hipStream_t stream)
{
    const float* node_emb = (const float*)d_in[0];
    const float* ew       = (const float*)d_in[1];
    const int*   src      = (const int*)d_in[2];
    const int*   dst      = (const int*)d_in[3];
    const float* W        = (const float*)d_in[4];
    float* out = (float*)d_out;

    const int n = in_sizes[0] / DIM;   // 100000
    const int E = in_sizes[1];         // 1600000
    const int nb = (n + 1023) >> 10;   // scan blocks

    // workspace layout (bytes, 256-aligned chunks)
    char* ws = (char*)d_ws;
    size_t oT    = 0;
    size_t oOff  = oT + (size_t)n * DIM * sizeof(float);            // T: 51.2 MB
    size_t offB  = ((size_t)(n + 1) * sizeof(int) + 255) & ~255ULL; // off: n+1 ints
    size_t oBsum = oOff + offB;
    size_t bsumB = ((size_t)nb * sizeof(int) + 255) & ~255ULL;
    size_t oCur  = oBsum + bsumB;
    size_t curB  = ((size_t)n * sizeof(int) + 255) & ~255ULL;
    size_t oSrc  = oCur + curB;
    size_t srcB  = ((size_t)E * sizeof(int) + 255) & ~255ULL;
    size_t oSw   = oSrc + srcB;

    float* T    = (float*)(ws + oT);
    int*   off  = (int*)(ws + oOff);
    int*   bsum = (int*)(ws + oBsum);
    int*   cur  = (int*)(ws + oCur);
    int*   ssrc = (int*)(ws + oSrc);
    float* sw   = (float*)(ws + oSw);

    // zero histogram + block sums (adjacent regions, one memset)
    hipMemsetAsync(ws + oOff, 0, offB + bsumB, stream);

    // T = node_emb @ W^T
    const int ntiles = (n + 127) >> 7;
    gnn_transform<<<ntiles, 256, 0, stream>>>(node_emb, W, T, n);

    // CSR build: histogram -> scan -> scatter
    const int eblk = (E + 255) / 256;
    edge_hist<<<eblk, 256, 0, stream>>>(dst, off, E);
    scan_phase1<<<nb, 256, 0, stream>>>(off, bsum, n);
    scan_phase2<<<1, 64, 0, stream>>>(bsum, nb);
    scan_phase3<<<nb, 256, 0, stream>>>(off, bsum, cur, n, E);
    edge_build<<<eblk, 256, 0, stream>>>(src, dst, ew, cur, ssrc, sw, E);

    // out[v] = sum_{e: dst=v} w_e * T[src_e]
    const int athreads = n * 32;
    gnn_aggregate<<<(athreads + 255) / 256, 256, 0, stream>>>(
        T, off, ssrc, sw, out, n);
}

// Round 3
// 418.640 us; speedup vs baseline: 6.7633x; 1.0876x over previous
//
#include <hip/hip_runtime.h>
#include <cstdint>

typedef unsigned short u16;
typedef unsigned int   u32;

#define DIM   128
#define BPAD  132

__device__ __forceinline__ u16 f2bf(float x) {   // fp32 -> bf16 RTNE
    u32 u = __float_as_uint(x);
    u32 r = u + 0x7FFFu + ((u >> 16) & 1u);
    return (u16)(r >> 16);
}

// ---------------------------------------------------------------------------
// Kernel 1: T(bf16) = node_emb @ W^T  (fp32 vector ALU; W staged in LDS)
// ---------------------------------------------------------------------------
__global__ __launch_bounds__(256) void gnn_transform(
    const float* __restrict__ A, const float* __restrict__ W,
    u16* __restrict__ Tb, int n)
{
    __shared__ float Bs[DIM * BPAD];
    {
        const int j  = threadIdx.x >> 1;
        const int k0 = (threadIdx.x & 1) << 6;
        const float* wr = W + j * DIM + k0;
#pragma unroll
        for (int k = 0; k < 64; k += 4) {
            float4 v = *(const float4*)(wr + k);
            Bs[(k0 + k + 0) * BPAD + j] = v.x;
            Bs[(k0 + k + 1) * BPAD + j] = v.y;
            Bs[(k0 + k + 2) * BPAD + j] = v.z;
            Bs[(k0 + k + 3) * BPAD + j] = v.w;
        }
    }
    __syncthreads();

    const int cg = threadIdx.x & 7;
    const int rg = threadIdx.x >> 3;
    const int ntiles = (n + 127) >> 7;

    for (int tile = blockIdx.x; tile < ntiles; tile += gridDim.x) {
        const int r0 = (tile << 7) + (rg << 2);
        float acc[4][16];
#pragma unroll
        for (int i = 0; i < 4; ++i)
#pragma unroll
            for (int m = 0; m < 16; ++m) acc[i][m] = 0.f;

        int rr[4];
#pragma unroll
        for (int i = 0; i < 4; ++i) {
            int r = r0 + i;
            rr[i] = (r < n) ? r : (n - 1);
        }

        for (int k0 = 0; k0 < DIM; k0 += 4) {
            float4 a[4];
#pragma unroll
            for (int i = 0; i < 4; ++i)
                a[i] = *(const float4*)(A + (size_t)rr[i] * DIM + k0);
#pragma unroll
            for (int kk = 0; kk < 4; ++kk) {
#pragma unroll
                for (int m = 0; m < 4; ++m) {
                    const float4 b = *(const float4*)(
                        &Bs[(k0 + kk) * BPAD + (cg << 2) + (m << 5)]);
#pragma unroll
                    for (int i = 0; i < 4; ++i) {
                        const float ak = (kk == 0) ? a[i].x :
                                         (kk == 1) ? a[i].y :
                                         (kk == 2) ? a[i].z : a[i].w;
                        acc[i][m * 4 + 0] += ak * b.x;
                        acc[i][m * 4 + 1] += ak * b.y;
                        acc[i][m * 4 + 2] += ak * b.z;
                        acc[i][m * 4 + 3] += ak * b.w;
                    }
                }
            }
        }
#pragma unroll
        for (int i = 0; i < 4; ++i) {
            const int r = r0 + i;
            if (r < n) {
                u16* o = Tb + (size_t)r * DIM;
#pragma unroll
                for (int m = 0; m < 4; ++m) {
                    ushort4 h;
                    h.x = f2bf(acc[i][m * 4 + 0]);
                    h.y = f2bf(acc[i][m * 4 + 1]);
                    h.z = f2bf(acc[i][m * 4 + 2]);
                    h.w = f2bf(acc[i][m * 4 + 3]);
                    *(ushort4*)(o + (cg << 2) + (m << 5)) = h;
                }
            }
        }
    }
}

// ---------------------------------------------------------------------------
// CSR build: histogram -> scan -> scatter of packed (src, w_bits) int2
// ---------------------------------------------------------------------------
__global__ __launch_bounds__(256) void edge_hist(
    const int* __restrict__ dst, int* __restrict__ cnt, int nE)
{
    const int i0 = (blockIdx.x * 256 + threadIdx.x) * 4;
    if (i0 + 3 < nE) {
        int4 d = *(const int4*)(dst + i0);
        atomicAdd(&cnt[d.x], 1); atomicAdd(&cnt[d.y], 1);
        atomicAdd(&cnt[d.z], 1); atomicAdd(&cnt[d.w], 1);
    } else {
        for (int i = i0; i < nE; ++i) atomicAdd(&cnt[dst[i]], 1);
    }
}

// per-1024-bin block sums
__global__ __launch_bounds__(256) void scan_phase1(
    const int* __restrict__ cnt, int* __restrict__ bsum, int n)
{
    const int base = blockIdx.x << 10;
    int s = 0;
    for (int i = threadIdx.x; i < 1024; i += 256) {
        int idx = base + i;
        if (idx < n) s += cnt[idx];
    }
    __shared__ int red[256];
    red[threadIdx.x] = s; __syncthreads();
    for (int o = 128; o; o >>= 1) {
        if (threadIdx.x < o) red[threadIdx.x] += red[threadIdx.x + o];
        __syncthreads();
    }
    if (threadIdx.x == 0) bsum[blockIdx.x] = red[0];
}

// exclusive scan of cnt -> off (in place); cur = off; off[n] = E.
// Each block computes its own prefix over bsum in parallel (no serial kernel).
__global__ __launch_bounds__(256) void scan_phase3(
    int* __restrict__ off, const int* __restrict__ bsum,
    int* __restrict__ cur, int n, int E, int nb)
{
    __shared__ int sc[256];
    __shared__ int pre;

    // parallel prefix of block sums: pre = sum_{i < blockIdx.x} bsum[i]
    {
        int s = 0;
        for (int i = threadIdx.x; i < blockIdx.x; i += 256) s += bsum[i];
        sc[threadIdx.x] = s; __syncthreads();
        for (int o = 128; o; o >>= 1) {
            if (threadIdx.x < o) sc[threadIdx.x] += sc[threadIdx.x + o];
            __syncthreads();
        }
        if (threadIdx.x == 0) pre = sc[0];
        __syncthreads();
    }

    const int base = blockIdx.x << 10;
    const int i0 = base + threadIdx.x * 4;
    int c[4]; int s = 0;
#pragma unroll
    for (int k = 0; k < 4; ++k) {
        int idx = i0 + k;
        c[k] = (idx < n) ? off[idx] : 0;
        s += c[k];
    }
    sc[threadIdx.x] = s; __syncthreads();
    for (int d = 1; d < 256; d <<= 1) {
        int v = (threadIdx.x >= d) ? sc[threadIdx.x - d] : 0;
        __syncthreads();
        sc[threadIdx.x] += v;
        __syncthreads();
    }
    int run = pre + (sc[threadIdx.x] - s);
#pragma unroll
    for (int k = 0; k < 4; ++k) {
        int idx = i0 + k;
        if (idx < n) { off[idx] = run; cur[idx] = run; run += c[k]; }
    }
    if (blockIdx.x == 0 && threadIdx.x == 0) off[n] = E;
}

__global__ __launch_bounds__(256) void edge_build(
    const int* __restrict__ src, const int* __restrict__ dst,
    const float* __restrict__ w, int* __restrict__ cur,
    int2* __restrict__ es, int nE)
{
    int i = blockIdx.x * 256 + threadIdx.x;
    if (i < nE) {
        int d = dst[i];
        int p = atomicAdd(&cur[d], 1);
        es[p] = make_int2(src[i], __float_as_int(w[i]));
    }
}

// ---------------------------------------------------------------------------
// Aggregate: 16 lanes/node; each lane gathers 16 B (8 bf16) of T[src],
// accumulates 8 fp32, stores the fp32 row once. No atomics.
// ---------------------------------------------------------------------------
__global__ __launch_bounds__(256) void gnn_aggregate(
    const u16* __restrict__ Tb, const int* __restrict__ off,
    const int2* __restrict__ es, float* __restrict__ out, int n)
{
    const int tid = blockIdx.x * 256 + threadIdx.x;
    const int v = tid >> 4;
    if (v >= n) return;
    const int lane = tid & 15;

    const int b = off[v], e = off[v + 1];
    float acc[8];
#pragma unroll
    for (int j = 0; j < 8; ++j) acc[j] = 0.f;

    const u32* Tw = (const u32*)Tb;   // 64 u32 per row, lane picks uint4

    for (int i = b; i < e; ++i) {
        const int2  ev = es[i];
        const float w  = __int_as_float(ev.y);
        const uint4 t  = ((const uint4*)(Tw + (size_t)ev.x * 64))[lane];
#pragma unroll
        for (int k = 0; k < 4; ++k) {
            const u32 u = (k == 0) ? t.x : (k == 1) ? t.y : (k == 2) ? t.z : t.w;
            const float flo = __uint_as_float(u << 16);
            const float fhi = __uint_as_float(u & 0xFFFF0000u);
            acc[2 * k + 0] += w * flo;
            acc[2 * k + 1] += w * fhi;
        }
    }

    float* o = out + (size_t)v * DIM + (lane << 3);
    *(float4*)(o + 0) = make_float4(acc[0], acc[1], acc[2], acc[3]);
    *(float4*)(o + 4) = make_float4(acc[4], acc[5], acc[6], acc[7]);
}

// ---------------------------------------------------------------------------
extern "C" void kernel_launch(void* const* d_in, const int* in_sizes, int n_in,
                              void* d_out, int out_size, void* d_ws, size_t ws_size,
                              hipStream_t stream)
{
    const float* node_emb = (const float*)d_in[0];
    const float* ew       = (const float*)d_in[1];
    const int*   src      = (const int*)d_in[2];
    const int*   dst      = (const int*)d_in[3];
    const float* W        = (const float*)d_in[4];
    float* out = (float*)d_out;

    const int n = in_sizes[0] / DIM;   // 100000
    const int E = in_sizes[1];         // 1600000
    const int nb = (n + 1023) >> 10;   // scan blocks (98)

    // workspace layout (256B-aligned chunks)
    char* ws = (char*)d_ws;
    size_t oT    = 0;
    size_t tB    = (((size_t)n * DIM * sizeof(u16)) + 255) & ~255ULL;  // 25.6 MB
    size_t oOff  = oT + tB;
    size_t offB  = (((size_t)(n + 1) * sizeof(int)) + 255) & ~255ULL;
    size_t oBsum = oOff + offB;
    size_t bsumB = (((size_t)nb * sizeof(int)) + 255) & ~255ULL;
    size_t oCur  = oBsum + bsumB;
    size_t curB  = (((size_t)n * sizeof(int)) + 255) & ~255ULL;
    size_t oEs   = oCur + curB;

    u16*  Tb   = (u16*)(ws + oT);
    int*  off  = (int*)(ws + oOff);
    int*  bsum = (int*)(ws + oBsum);
    int*  cur  = (int*)(ws + oCur);
    int2* es   = (int2*)(ws + oEs);

    // zero histogram + block sums (adjacent, one memset)
    hipMemsetAsync(ws + oOff, 0, offB + bsumB, stream);

    // T = node_emb @ W^T  (bf16 out)
    const int ntiles = (n + 127) >> 7;
    gnn_transform<<<ntiles, 256, 0, stream>>>(node_emb, W, Tb, n);

    // CSR build
    const int hblk = (E + 1023) / 1024;
    edge_hist<<<hblk, 256, 0, stream>>>(dst, off, E);
    scan_phase1<<<nb, 256, 0, stream>>>(off, bsum, n);
    scan_phase3<<<nb, 256, 0, stream>>>(off, bsum, cur, n, E, nb);
    const int eblk = (E + 255) / 256;
    edge_build<<<eblk, 256, 0, stream>>>(src, dst, ew, cur, es, E);

    // out[v] = sum_{e: dst=v} w_e * T[src_e]
    const int athreads = n * 16;
    gnn_aggregate<<<(athreads + 255) / 256, 256, 0, stream>>>(
        Tb, off, es, out, n);
}

// Round 4
// 353.590 us; speedup vs baseline: 8.0075x; 1.1840x over previous
//
#include <hip/hip_runtime.h>
#include <cstdint>

typedef unsigned short u16;
typedef unsigned int   u32;

#define DIM     128
#define BPAD    132
#define BSH     9            // nodes per fine bucket = 512
#define BSIZE   512
#define NBK_MAX 256          // supports n <= 131072
#define CHUNK   8192         // edges per L1 sort block

__device__ __forceinline__ u16 f2bf(float x) {   // fp32 -> bf16 RTNE
    u32 u = __float_as_uint(x);
    u32 r = u + 0x7FFFu + ((u >> 16) & 1u);
    return (u16)(r >> 16);
}

// ---------------------------------------------------------------------------
// K1 (fat kernel): blocks [0, nCntBlk) do the L1 bucket count;
// blocks [nCntBlk, nCntBlk+ntiles) compute T(bf16) = node_emb @ W^T.
// The count part is latency-bound, the transform VALU-bound -> they overlap.
// ---------------------------------------------------------------------------
__global__ __launch_bounds__(256) void k_count_transform(
    const float* __restrict__ A, const float* __restrict__ W,
    u16* __restrict__ Tb,
    const int* __restrict__ dst, int* __restrict__ cnt,
    int n, int E, int nCntBlk, int NBK)
{
    __shared__ float Bs[DIM * BPAD];

    if (blockIdx.x < nCntBlk) {
        // ---- L1 count: histogram of dst>>BSH over this block's edge chunk
        int* hist = (int*)Bs;
        for (int i = threadIdx.x; i < NBK; i += 256) hist[i] = 0;
        __syncthreads();
        const int base = blockIdx.x * CHUNK;
        const int end  = min(base + CHUNK, E);
        for (int i = base + threadIdx.x; i < end; i += 256)
            atomicAdd(&hist[dst[i] >> BSH], 1);
        __syncthreads();
        for (int b = threadIdx.x; b < NBK; b += 256)
            cnt[b * nCntBlk + blockIdx.x] = hist[b];
        return;
    }

    // ---- transform: T[r][j] = sum_k A[r][k] * W[j][k], bf16 out
    {
        const int j  = threadIdx.x >> 1;
        const int k0 = (threadIdx.x & 1) << 6;
        const float* wr = W + j * DIM + k0;
#pragma unroll
        for (int k = 0; k < 64; k += 4) {
            float4 v = *(const float4*)(wr + k);
            Bs[(k0 + k + 0) * BPAD + j] = v.x;
            Bs[(k0 + k + 1) * BPAD + j] = v.y;
            Bs[(k0 + k + 2) * BPAD + j] = v.z;
            Bs[(k0 + k + 3) * BPAD + j] = v.w;
        }
    }
    __syncthreads();

    const int cg = threadIdx.x & 7;
    const int rg = threadIdx.x >> 3;
    const int tile = blockIdx.x - nCntBlk;
    const int r0 = (tile << 7) + (rg << 2);

    float acc[4][16];
#pragma unroll
    for (int i = 0; i < 4; ++i)
#pragma unroll
        for (int m = 0; m < 16; ++m) acc[i][m] = 0.f;

    int rr[4];
#pragma unroll
    for (int i = 0; i < 4; ++i) {
        int r = r0 + i;
        rr[i] = (r < n) ? r : (n - 1);
    }

    for (int k0 = 0; k0 < DIM; k0 += 4) {
        float4 a[4];
#pragma unroll
        for (int i = 0; i < 4; ++i)
            a[i] = *(const float4*)(A + (size_t)rr[i] * DIM + k0);
#pragma unroll
        for (int kk = 0; kk < 4; ++kk) {
#pragma unroll
            for (int m = 0; m < 4; ++m) {
                const float4 b = *(const float4*)(
                    &Bs[(k0 + kk) * BPAD + (cg << 2) + (m << 5)]);
#pragma unroll
                for (int i = 0; i < 4; ++i) {
                    const float ak = (kk == 0) ? a[i].x :
                                     (kk == 1) ? a[i].y :
                                     (kk == 2) ? a[i].z : a[i].w;
                    acc[i][m * 4 + 0] += ak * b.x;
                    acc[i][m * 4 + 1] += ak * b.y;
                    acc[i][m * 4 + 2] += ak * b.z;
                    acc[i][m * 4 + 3] += ak * b.w;
                }
            }
        }
    }
#pragma unroll
    for (int i = 0; i < 4; ++i) {
        const int r = r0 + i;
        if (r < n) {
            u16* o = Tb + (size_t)r * DIM;
#pragma unroll
            for (int m = 0; m < 4; ++m) {
                ushort4 h;
                h.x = f2bf(acc[i][m * 4 + 0]);
                h.y = f2bf(acc[i][m * 4 + 1]);
                h.z = f2bf(acc[i][m * 4 + 2]);
                h.w = f2bf(acc[i][m * 4 + 3]);
                *(ushort4*)(o + (cg << 2) + (m << 5)) = h;
            }
        }
    }
}

// ---------------------------------------------------------------------------
// K2: exclusive scan of cnt[NBK * nCntBlk] (bucket-major) in place; also
// emits bucketStart[b] = prefix at cnt[b*nCntBlk], bucketStart[NBK] = E.
// Single block; M ~= 38k values.
// ---------------------------------------------------------------------------
__global__ __launch_bounds__(256) void k_scan(
    int* __restrict__ cnt, int* __restrict__ bucketStart,
    int M, int nCntBlk, int NBK, int E)
{
    __shared__ int sums[256];
    const int t = threadIdx.x;
    const int clen = (M + 255) >> 8;
    const int i0 = t * clen, i1 = min(i0 + clen, M);

    int s = 0;
    for (int i = i0; i < i1; ++i) s += cnt[i];
    sums[t] = s; __syncthreads();
    for (int d = 1; d < 256; d <<= 1) {
        int v = (t >= d) ? sums[t - d] : 0;
        __syncthreads();
        sums[t] += v;
        __syncthreads();
    }
    int run = sums[t] - s;
    for (int i = i0; i < i1; ++i) { int c = cnt[i]; cnt[i] = run; run += c; }
    __syncthreads();
    for (int b = t; b < NBK; b += 256) bucketStart[b] = cnt[b * nCntBlk];
    if (t == 0) bucketStart[NBK] = E;
}

// ---------------------------------------------------------------------------
// K3: L1 scatter. Each block writes its edges into per-(bucket,block)
// contiguous runs -> block-exclusive lines, L2 write-back absorbs.
// Payload: x = src | (dst&511)<<20, y = w bits.
// ---------------------------------------------------------------------------
__global__ __launch_bounds__(256) void k_scatter(
    const int* __restrict__ src, const int* __restrict__ dst,
    const float* __restrict__ w, const int* __restrict__ cnt,
    int2* __restrict__ es1, int E, int nCntBlk, int NBK)
{
    __shared__ int lpos[NBK_MAX];
    for (int b = threadIdx.x; b < NBK; b += 256)
        lpos[b] = cnt[b * nCntBlk + blockIdx.x];
    __syncthreads();
    const int base = blockIdx.x * CHUNK;
    const int end  = min(base + CHUNK, E);
    for (int i = base + threadIdx.x; i < end; i += 256) {
        const int d = dst[i];
        const int p = atomicAdd(&lpos[d >> BSH], 1);
        es1[p] = make_int2(src[i] | ((d & (BSIZE - 1)) << 20),
                           __float_as_int(w[i]));
    }
}

// ---------------------------------------------------------------------------
// K4: fine sort within a bucket (512 nodes, ~8192 edges, 64 KB window,
// block-exclusive). Builds exact CSR off[] and final es2 (dlocal stripped).
// ---------------------------------------------------------------------------
__global__ __launch_bounds__(256) void k_fine(
    const int2* __restrict__ es1, const int* __restrict__ bucketStart,
    int2* __restrict__ es2, int* __restrict__ off, int n, int NBK)
{
    __shared__ int c[BSIZE];
    __shared__ int cur[BSIZE];
    __shared__ int sums[256];

    const int b = blockIdx.x;
    const int s = bucketStart[b], e = bucketStart[b + 1];
    const int t = threadIdx.x;

    c[2 * t] = 0; c[2 * t + 1] = 0;
    __syncthreads();
    for (int i = s + t; i < e; i += 256)
        atomicAdd(&c[es1[i].x >> 20], 1);
    __syncthreads();

    // exclusive scan over 512 counters (thread owns 2)
    const int c0 = c[2 * t], c1 = c[2 * t + 1];
    const int ts = c0 + c1;
    sums[t] = ts; __syncthreads();
    for (int d = 1; d < 256; d <<= 1) {
        int v = (t >= d) ? sums[t - d] : 0;
        __syncthreads();
        sums[t] += v;
        __syncthreads();
    }
    const int pre = sums[t] - ts;
    const int p0 = s + pre, p1 = s + pre + c0;
    cur[2 * t] = p0; cur[2 * t + 1] = p1;

    const int nodeBase = b << BSH;
    const int v0 = nodeBase + 2 * t, v1 = v0 + 1;
    if (v0 < n) off[v0] = p0;
    if (v1 < n) off[v1] = p1;
    if (b == NBK - 1 && t == 0) off[n] = e;   // e == E for the last bucket
    __syncthreads();

    for (int i = s + t; i < e; i += 256) {
        const int2 ev = es1[i];
        const int p = atomicAdd(&cur[ev.x >> 20], 1);
        es2[p] = make_int2(ev.x & 0xFFFFF, ev.y);
    }
}

// ---------------------------------------------------------------------------
// K5: aggregate. 16 lanes/node; lane gathers 16 B (8 bf16) of T[src],
// fp32 accumulate, single store per node. No atomics.
// ---------------------------------------------------------------------------
__global__ __launch_bounds__(256) void gnn_aggregate(
    const u16* __restrict__ Tb, const int* __restrict__ off,
    const int2* __restrict__ es, float* __restrict__ out, int n)
{
    const int tid = blockIdx.x * 256 + threadIdx.x;
    const int v = tid >> 4;
    if (v >= n) return;
    const int lane = tid & 15;

    const int b = off[v], e = off[v + 1];
    float acc[8];
#pragma unroll
    for (int j = 0; j < 8; ++j) acc[j] = 0.f;

    const u32* Tw = (const u32*)Tb;

    for (int i = b; i < e; ++i) {
        const int2  ev = es[i];
        const float w  = __int_as_float(ev.y);
        const uint4 t  = ((const uint4*)(Tw + (size_t)ev.x * 64))[lane];
#pragma unroll
        for (int k = 0; k < 4; ++k) {
            const u32 u = (k == 0) ? t.x : (k == 1) ? t.y : (k == 2) ? t.z : t.w;
            acc[2 * k + 0] += w * __uint_as_float(u << 16);
            acc[2 * k + 1] += w * __uint_as_float(u & 0xFFFF0000u);
        }
    }

    float* o = out + (size_t)v * DIM + (lane << 3);
    *(float4*)(o + 0) = make_float4(acc[0], acc[1], acc[2], acc[3]);
    *(float4*)(o + 4) = make_float4(acc[4], acc[5], acc[6], acc[7]);
}

// ---------------------------------------------------------------------------
extern "C" void kernel_launch(void* const* d_in, const int* in_sizes, int n_in,
                              void* d_out, int out_size, void* d_ws, size_t ws_size,
                              hipStream_t stream)
{
    const float* node_emb = (const float*)d_in[0];
    const float* ew       = (const float*)d_in[1];
    const int*   src      = (const int*)d_in[2];
    const int*   dst      = (const int*)d_in[3];
    const float* W        = (const float*)d_in[4];
    float* out = (float*)d_out;

    const int n = in_sizes[0] / DIM;            // 100000
    const int E = in_sizes[1];                  // 1600000
    const int NBK = (n + BSIZE - 1) >> BSH;     // 196 fine buckets
    const int nCntBlk = (E + CHUNK - 1) / CHUNK;// 196 L1 blocks
    const int M = NBK * nCntBlk;                // count-matrix size

    // workspace layout (256B-aligned chunks)
    char* ws = (char*)d_ws;
    size_t o = 0;
    u16* Tb = (u16*)(ws + o);  o += (((size_t)n * DIM * sizeof(u16)) + 255) & ~255ULL;
    int* cnt = (int*)(ws + o); o += (((size_t)M * sizeof(int)) + 255) & ~255ULL;
    int* bucketStart = (int*)(ws + o); o += (((size_t)(NBK + 1) * sizeof(int)) + 255) & ~255ULL;
    int* off = (int*)(ws + o); o += (((size_t)(n + 1) * sizeof(int)) + 255) & ~255ULL;
    int2* es1 = (int2*)(ws + o); o += (((size_t)E * sizeof(int2)) + 255) & ~255ULL;
    int2* es2 = (int2*)(ws + o);

    const int ntiles = (n + 127) >> 7;

    // K1: fused L1-count + transform (no memsets needed anywhere)
    k_count_transform<<<nCntBlk + ntiles, 256, 0, stream>>>(
        node_emb, W, Tb, dst, cnt, n, E, nCntBlk, NBK);

    // K2: scan counts -> run offsets + bucketStart
    k_scan<<<1, 256, 0, stream>>>(cnt, bucketStart, M, nCntBlk, NBK, E);

    // K3: L1 scatter into block-exclusive runs
    k_scatter<<<nCntBlk, 256, 0, stream>>>(src, dst, ew, cnt, es1, E, nCntBlk, NBK);

    // K4: fine sort within buckets -> exact CSR (off, es2)
    k_fine<<<NBK, 256, 0, stream>>>(es1, bucketStart, es2, off, n, NBK);

    // K5: aggregate
    const int athreads = n * 16;
    gnn_aggregate<<<(athreads + 255) / 256, 256, 0, stream>>>(
        Tb, off, es2, out, n);
}

// Round 5
// 269.167 us; speedup vs baseline: 10.5190x; 1.3136x over previous
//
#include <hip/hip_runtime.h>
#include <cstdint>

typedef unsigned short u16;
typedef unsigned int   u32;

#define DIM     128
#define TPITCH  136          // LDS W row pitch in bf16 (bank-spread)
#define BSH     9            // nodes per fine bucket = 512
#define BSIZE   512
#define NBK_MAX 256          // supports n <= 131072
#define CHUNK   8192         // edges per L1 sort block

__device__ __forceinline__ u16 f2bf(float x) {   // fp32 -> bf16 RTNE
    u32 u = __float_as_uint(x);
    u32 r = u + 0x7FFFu + ((u >> 16) & 1u);
    return (u16)(r >> 16);
}

typedef __attribute__((ext_vector_type(8))) short bfrag;
typedef __attribute__((ext_vector_type(4))) float f32x4;

// ---------------------------------------------------------------------------
// K1 (fat): blocks [0, nCntBlk) do the L1 bucket count; the rest compute
// T(bf16) = A @ W^T with mfma_f32_16x16x32_bf16 (A, W cast to bf16 in-flight).
// Each wave: 16 rows x 128 cols (8 col-tiles, 4 k-steps, 32 MFMA).
// ---------------------------------------------------------------------------
__global__ __launch_bounds__(256) void k_count_transform(
    const float* __restrict__ A, const float* __restrict__ W,
    u16* __restrict__ Tb,
    const int* __restrict__ dst, int* __restrict__ cnt,
    int n, int E, int nCntBlk, int NBK)
{
    __shared__ u16 Wb[DIM * TPITCH];   // 34816 B; count blocks reuse as hist

    if (blockIdx.x < nCntBlk) {
        int* hist = (int*)Wb;
        for (int i = threadIdx.x; i < NBK; i += 256) hist[i] = 0;
        __syncthreads();
        const int base = blockIdx.x * CHUNK;
        const int end  = min(base + CHUNK, E);
        for (int i = base + threadIdx.x; i < end; i += 256)
            atomicAdd(&hist[dst[i] >> BSH], 1);
        __syncthreads();
        for (int b = threadIdx.x; b < NBK; b += 256)
            cnt[b * nCntBlk + blockIdx.x] = hist[b];
        return;
    }

    // stage W as bf16: Wb[j][k] = bf16(W[j][k]); thread t -> row t>>1, half (t&1)*64
    {
        const int j  = threadIdx.x >> 1;
        const int k0 = (threadIdx.x & 1) << 6;
        const float* wr = W + j * DIM + k0;
        u16* wo = Wb + j * TPITCH + k0;
#pragma unroll
        for (int k = 0; k < 64; k += 4) {
            float4 v = *(const float4*)(wr + k);
            ushort4 h;
            h.x = f2bf(v.x); h.y = f2bf(v.y); h.z = f2bf(v.z); h.w = f2bf(v.w);
            *(ushort4*)(wo + k) = h;
        }
    }
    __syncthreads();

    const int wave = threadIdx.x >> 6;
    const int lane = threadIdx.x & 63;
    const int quad = lane >> 4;
    const int l16  = lane & 15;

    const int r0 = (((blockIdx.x - nCntBlk) << 2) + wave) << 4;  // 16 rows/wave
    if (r0 >= n) return;                       // wave-uniform, after all barriers

    const int ar = min(r0 + l16, n - 1);       // A-frag row (clamped on tail)
    const float* arow = A + (size_t)ar * DIM;

    f32x4 acc[8];
#pragma unroll
    for (int c = 0; c < 8; ++c) acc[c] = (f32x4)(0.f);

#pragma unroll
    for (int s = 0; s < 4; ++s) {
        const int koff = (s << 5) + (quad << 3);
        const float4 f0 = *(const float4*)(arow + koff);
        const float4 f1 = *(const float4*)(arow + koff + 4);
        bfrag a;
        a[0] = (short)f2bf(f0.x); a[1] = (short)f2bf(f0.y);
        a[2] = (short)f2bf(f0.z); a[3] = (short)f2bf(f0.w);
        a[4] = (short)f2bf(f1.x); a[5] = (short)f2bf(f1.y);
        a[6] = (short)f2bf(f1.z); a[7] = (short)f2bf(f1.w);
#pragma unroll
        for (int c = 0; c < 8; ++c) {
            const int nn = (c << 4) + l16;     // B col; B[k][n] = W[n][k]
            const bfrag b = *(const bfrag*)(Wb + nn * TPITCH + koff);
            acc[c] = __builtin_amdgcn_mfma_f32_16x16x32_bf16(a, b, acc[c], 0, 0, 0);
        }
    }

    // D[row][col]: row = r0 + quad*4 + r, col = c*16 + l16
#pragma unroll
    for (int r = 0; r < 4; ++r) {
        const int row = r0 + (quad << 2) + r;
        if (row < n) {
            u16* orow = Tb + (size_t)row * DIM + l16;
#pragma unroll
            for (int c = 0; c < 8; ++c)
                orow[c << 4] = f2bf(acc[c][r]);
        }
    }
}

// ---------------------------------------------------------------------------
// K2a: tot[b] = sum of cnt row b (nCntBlk values)
// ---------------------------------------------------------------------------
__global__ __launch_bounds__(256) void k_rowsum(
    const int* __restrict__ cnt, int* __restrict__ tot, int nCntBlk)
{
    __shared__ int red[256];
    const int t = threadIdx.x;
    const int* row = cnt + blockIdx.x * nCntBlk;
    int s = 0;
    for (int i = t; i < nCntBlk; i += 256) s += row[i];
    red[t] = s; __syncthreads();
    for (int o = 128; o; o >>= 1) {
        if (t < o) red[t] += red[t + o];
        __syncthreads();
    }
    if (t == 0) tot[blockIdx.x] = red[0];
}

// ---------------------------------------------------------------------------
// K2b: bucketStart = exclusive scan of tot (NBK <= 256); bucketStart[NBK]=E
// ---------------------------------------------------------------------------
__global__ __launch_bounds__(256) void k_scan_buckets(
    const int* __restrict__ tot, int* __restrict__ bucketStart, int NBK, int E)
{
    __shared__ int sc[256];
    const int t = threadIdx.x;
    const int v = (t < NBK) ? tot[t] : 0;
    sc[t] = v; __syncthreads();
    for (int d = 1; d < 256; d <<= 1) {
        int u = (t >= d) ? sc[t - d] : 0;
        __syncthreads();
        sc[t] += u;
        __syncthreads();
    }
    if (t < NBK) bucketStart[t] = sc[t] - v;
    if (t == 0) bucketStart[NBK] = E;
}

// ---------------------------------------------------------------------------
// K2c: cnt row b -> bucketStart[b] + exclusive scan of the row (in place)
// (requires nCntBlk <= 256)
// ---------------------------------------------------------------------------
__global__ __launch_bounds__(256) void k_rowscan(
    int* __restrict__ cnt, const int* __restrict__ bucketStart, int nCntBlk)
{
    __shared__ int sc[256];
    const int t = threadIdx.x;
    int* row = cnt + blockIdx.x * nCntBlk;
    const int v = (t < nCntBlk) ? row[t] : 0;
    sc[t] = v; __syncthreads();
    for (int d = 1; d < 256; d <<= 1) {
        int u = (t >= d) ? sc[t - d] : 0;
        __syncthreads();
        sc[t] += u;
        __syncthreads();
    }
    if (t < nCntBlk) row[t] = bucketStart[blockIdx.x] + sc[t] - v;
}

// ---------------------------------------------------------------------------
// K3: L1 scatter into per-(bucket,block) contiguous block-exclusive runs.
// Payload: x = src | (dst&511)<<20, y = w bits.
// ---------------------------------------------------------------------------
__global__ __launch_bounds__(256) void k_scatter(
    const int* __restrict__ src, const int* __restrict__ dst,
    const float* __restrict__ w, const int* __restrict__ cnt,
    int2* __restrict__ es1, int E, int nCntBlk, int NBK)
{
    __shared__ int lpos[NBK_MAX];
    for (int b = threadIdx.x; b < NBK; b += 256)
        lpos[b] = cnt[b * nCntBlk + blockIdx.x];
    __syncthreads();
    const int base = blockIdx.x * CHUNK;
    const int end  = min(base + CHUNK, E);
    for (int i = base + threadIdx.x; i < end; i += 256) {
        const int d = dst[i];
        const int p = atomicAdd(&lpos[d >> BSH], 1);
        es1[p] = make_int2(src[i] | ((d & (BSIZE - 1)) << 20),
                           __float_as_int(w[i]));
    }
}

// ---------------------------------------------------------------------------
// K4: fine sort within a bucket (512 nodes, block-exclusive 64 KB window):
// exact CSR off[] + final es2 (dlocal stripped).
// ---------------------------------------------------------------------------
__global__ __launch_bounds__(256) void k_fine(
    const int2* __restrict__ es1, const int* __restrict__ bucketStart,
    int2* __restrict__ es2, int* __restrict__ off, int n, int NBK)
{
    __shared__ int c[BSIZE];
    __shared__ int cur[BSIZE];
    __shared__ int sums[256];

    const int b = blockIdx.x;
    const int s = bucketStart[b], e = bucketStart[b + 1];
    const int t = threadIdx.x;

    c[2 * t] = 0; c[2 * t + 1] = 0;
    __syncthreads();
    for (int i = s + t; i < e; i += 256)
        atomicAdd(&c[es1[i].x >> 20], 1);
    __syncthreads();

    const int c0 = c[2 * t], c1 = c[2 * t + 1];
    const int ts = c0 + c1;
    sums[t] = ts; __syncthreads();
    for (int d = 1; d < 256; d <<= 1) {
        int v = (t >= d) ? sums[t - d] : 0;
        __syncthreads();
        sums[t] += v;
        __syncthreads();
    }
    const int pre = sums[t] - ts;
    const int p0 = s + pre, p1 = s + pre + c0;
    cur[2 * t] = p0; cur[2 * t + 1] = p1;

    const int v0 = (b << BSH) + 2 * t, v1 = v0 + 1;
    if (v0 < n) off[v0] = p0;
    if (v1 < n) off[v1] = p1;
    if (b == NBK - 1 && t == 0) off[n] = e;
    __syncthreads();

    for (int i = s + t; i < e; i += 256) {
        const int2 ev = es1[i];
        const int p = atomicAdd(&cur[ev.x >> 20], 1);
        es2[p] = make_int2(ev.x & 0xFFFFF, ev.y);
    }
}

// ---------------------------------------------------------------------------
// K5: aggregate. One 64-lane wave per node; lane holds 1 dword (2 bf16) of
// the row; unroll-4 for MLP. Single coalesced float2 store per node row.
// ---------------------------------------------------------------------------
__global__ __launch_bounds__(256) void gnn_aggregate(
    const u16* __restrict__ Tb, const int* __restrict__ off,
    const int2* __restrict__ es, float* __restrict__ out, int n)
{
    const int v = blockIdx.x * 4 + (threadIdx.x >> 6);
    if (v >= n) return;
    const int lane = threadIdx.x & 63;
    const u32* Tw = (const u32*)Tb;

    const int b = off[v], e = off[v + 1];
    float ax = 0.f, ay = 0.f;

    int i = b;
    for (; i + 3 < e; i += 4) {
        const int2 e0 = es[i], e1 = es[i + 1], e2 = es[i + 2], e3 = es[i + 3];
        const u32 t0 = Tw[(size_t)e0.x * 64 + lane];
        const u32 t1 = Tw[(size_t)e1.x * 64 + lane];
        const u32 t2 = Tw[(size_t)e2.x * 64 + lane];
        const u32 t3 = Tw[(size_t)e3.x * 64 + lane];
        const float w0 = __int_as_float(e0.y), w1 = __int_as_float(e1.y);
        const float w2 = __int_as_float(e2.y), w3 = __int_as_float(e3.y);
        ax += w0 * __uint_as_float(t0 << 16);
        ay += w0 * __uint_as_float(t0 & 0xFFFF0000u);
        ax += w1 * __uint_as_float(t1 << 16);
        ay += w1 * __uint_as_float(t1 & 0xFFFF0000u);
        ax += w2 * __uint_as_float(t2 << 16);
        ay += w2 * __uint_as_float(t2 & 0xFFFF0000u);
        ax += w3 * __uint_as_float(t3 << 16);
        ay += w3 * __uint_as_float(t3 & 0xFFFF0000u);
    }
    for (; i < e; ++i) {
        const int2 ev = es[i];
        const u32 t = Tw[(size_t)ev.x * 64 + lane];
        const float w = __int_as_float(ev.y);
        ax += w * __uint_as_float(t << 16);
        ay += w * __uint_as_float(t & 0xFFFF0000u);
    }

    *(float2*)(out + (size_t)v * DIM + 2 * lane) = make_float2(ax, ay);
}

// ---------------------------------------------------------------------------
extern "C" void kernel_launch(void* const* d_in, const int* in_sizes, int n_in,
                              void* d_out, int out_size, void* d_ws, size_t ws_size,
                              hipStream_t stream)
{
    const float* node_emb = (const float*)d_in[0];
    const float* ew       = (const float*)d_in[1];
    const int*   src      = (const int*)d_in[2];
    const int*   dst      = (const int*)d_in[3];
    const float* W        = (const float*)d_in[4];
    float* out = (float*)d_out;

    const int n = in_sizes[0] / DIM;            // 100000
    const int E = in_sizes[1];                  // 1600000
    const int NBK = (n + BSIZE - 1) >> BSH;     // 196 fine buckets
    const int nCntBlk = (E + CHUNK - 1) / CHUNK;// 196 L1 blocks
    const int M = NBK * nCntBlk;

    // workspace layout (256B-aligned chunks)
    char* ws = (char*)d_ws;
    size_t o = 0;
    u16* Tb = (u16*)(ws + o);  o += (((size_t)n * DIM * sizeof(u16)) + 255) & ~255ULL;
    int* cnt = (int*)(ws + o); o += (((size_t)M * sizeof(int)) + 255) & ~255ULL;
    int* tot = (int*)(ws + o); o += (((size_t)NBK * sizeof(int)) + 255) & ~255ULL;
    int* bucketStart = (int*)(ws + o); o += (((size_t)(NBK + 1) * sizeof(int)) + 255) & ~255ULL;
    int* off = (int*)(ws + o); o += (((size_t)(n + 1) * sizeof(int)) + 255) & ~255ULL;
    int2* es1 = (int2*)(ws + o); o += (((size_t)E * sizeof(int2)) + 255) & ~255ULL;
    int2* es2 = (int2*)(ws + o);

    const int ntiles = (n + 63) >> 6;           // 64 rows per transform block

    // K1: fused L1-count + MFMA transform
    k_count_transform<<<nCntBlk + ntiles, 256, 0, stream>>>(
        node_emb, W, Tb, dst, cnt, n, E, nCntBlk, NBK);

    // K2: parallel scan of the count matrix
    k_rowsum<<<NBK, 256, 0, stream>>>(cnt, tot, nCntBlk);
    k_scan_buckets<<<1, 256, 0, stream>>>(tot, bucketStart, NBK, E);
    k_rowscan<<<NBK, 256, 0, stream>>>(cnt, bucketStart, nCntBlk);

    // K3: L1 scatter into block-exclusive runs
    k_scatter<<<nCntBlk, 256, 0, stream>>>(src, dst, ew, cnt, es1, E, nCntBlk, NBK);

    // K4: fine sort within buckets -> exact CSR (off, es2)
    k_fine<<<NBK, 256, 0, stream>>>(es1, bucketStart, es2, off, n, NBK);

    // K5: aggregate (one wave per node)
    gnn_aggregate<<<(n + 3) / 4, 256, 0, stream>>>(Tb, off, es2, out, n);
}